// Round 4
// baseline (63.125 us; speedup 1.0000x reference)
//
#include <hip/hip_runtime.h>
#include <hip/hip_bf16.h>

// SimCLR loss, MI355X. N=8192 rows, D=128, T=0.5.
// normalize(f32->bf16) -> fused sim-GEMM + sum(exp(2*dot)) (MFMA bf16, fixed-max
// logsumexp since |sim|<=2; A-fragments PINNED in VGPRs, B staged in LDS via
// global_load_lds + XOR swizzle, double-buffered) -> per-row loss -> reduce.

#define BATCH 4096
#define N_TOT 8192
#define DIM 128
#define ROWS_PER_WAVE 64
#define ROWS_PER_BLK 256                 // 4 waves
#define NROWBLK (N_TOT / ROWS_PER_BLK)   // 32
#define TILE_C 64                        // cols per LDS B-tile (16 KB)

// exp(2d) == exp2(d * 2/ln2)
#define C_LOG2E2 2.8853900817779268f

using bf16x8 = __attribute__((ext_vector_type(8))) __bf16;
using f32x4  = __attribute__((ext_vector_type(4))) float;

typedef __attribute__((address_space(1))) const void cg_void;
typedef __attribute__((address_space(3))) void lds_void;
__device__ __forceinline__ void gll16(const void* g, void* l) {
    __builtin_amdgcn_global_load_lds((cg_void*)g, (lds_void*)l, 16, 0, 0);
}

// ---------------- kernel 1: normalize rows, write bf16 ----------------
__global__ __launch_bounds__(256) void k_normalize(const float* __restrict__ zi,
                                                   const float* __restrict__ zj,
                                                   __hip_bfloat16* __restrict__ zn) {
    int row  = blockIdx.x * 4 + (threadIdx.x >> 6);
    int lane = threadIdx.x & 63;
    const float* src = (row < BATCH) ? (zi + (size_t)row * DIM)
                                     : (zj + (size_t)(row - BATCH) * DIM);
    float2 v = ((const float2*)src)[lane];
    float ss = v.x * v.x + v.y * v.y;
    #pragma unroll
    for (int m = 1; m < 64; m <<= 1) ss += __shfl_xor(ss, m);
    float inv = 1.0f / fmaxf(sqrtf(ss), 1e-8f);
    __hip_bfloat162 o;
    o.x = __float2bfloat16(v.x * inv);
    o.y = __float2bfloat16(v.y * inv);
    ((__hip_bfloat162*)(zn + (size_t)row * DIM))[lane] = o;
}

// ---------------- kernel 2: fused sim GEMM + sum of exp(2*dot) ----------------
// Block: 4 waves x 64 rows. A-fragments live in VGPRs for the whole kernel,
// pinned with an empty asm so the compiler cannot re-load them from global
// (R1-R3 were latency-bound on exactly that remat: VGPR_Count 84 << 64-reg A).
// B: 64-col tiles staged in LDS, double-buffered, XOR-swizzled (rule #21:
// linear LDS dest + inverse-swizzled global src + swizzled ds_read).
template <int NCS>
__global__ __launch_bounds__(256, 4) void k_main(const __hip_bfloat16* __restrict__ zn_,
                                                 float* __restrict__ S_part) {
    constexpr int STRIP = N_TOT / NCS;       // cols per block strip
    constexpr int NT    = STRIP / TILE_C;    // B-tiles per block

    __shared__ __align__(16) char Bs[2][TILE_C * 256];

    const int tid  = threadIdx.x;
    const int lane = tid & 63;
    const int wv   = tid >> 6;
    const int l15  = lane & 15;
    const int lb   = lane >> 4;                       // 0..3
    const int wr0  = blockIdx.x * ROWS_PER_BLK + wv * ROWS_PER_WAVE;
    const int cs0  = blockIdx.y * STRIP;

    const __bf16* zn = (const __bf16*)zn_;

    // A fragments: rows wr0 + g*16 + l15, k-slice s: k = s*32 + lb*8 .. +7
    f32x4 a_[4][4];
    #pragma unroll
    for (int g = 0; g < 4; ++g) {
        const __bf16* p = zn + (size_t)(wr0 + g * 16 + l15) * DIM + lb * 8;
        #pragma unroll
        for (int s = 0; s < 4; ++s)
            a_[g][s] = *(const f32x4*)(p + s * 32);
    }
    // pin: forces residency, forbids rematerialization-from-global
    #pragma unroll
    for (int g = 0; g < 4; ++g)
        #pragma unroll
        for (int s = 0; s < 4; ++s)
            asm("" : "+v"(a_[g][s]));

    // staging source offsets: this wave fills 16B-granules m = (wv*4+i)*64 + lane
    const char* gB = (const char*)(zn + (size_t)cs0 * DIM);
    int srcoff[4];
    #pragma unroll
    for (int i = 0; i < 4; ++i) {
        int m = (wv * 4 + i) * 64 + lane;
        int c = m >> 4, slot = m & 15;
        int j = slot ^ (c & 7);
        srcoff[i] = c * 256 + j * 16;
    }

    auto STAGE = [&](int t) {
        const char* src = gB + (size_t)t * (TILE_C * 256);
        char* dst = Bs[t & 1];
        #pragma unroll
        for (int i = 0; i < 4; ++i)
            gll16(src + srcoff[i], dst + (wv * 4 + i) * 1024);
    };

    f32x4 sumexp[4] = {};                             // [g] -> 4 rows each

    auto COMPUTE = [&](int t) {
        const char* buf = Bs[t & 1];
        const int c0t = cs0 + t * TILE_C;
        const bool diagtile = (c0t == wr0);           // wave-uniform
        #pragma unroll
        for (int cb = 0; cb < 4; ++cb) {
            const int c = cb * 16 + l15;              // local col
            const char* pc = buf + c * 256;
            bf16x8 b[4];
            #pragma unroll
            for (int s = 0; s < 4; ++s)
                b[s] = *(const bf16x8*)(pc + ((lb + s * 4) ^ (c & 7)) * 16);
            f32x4 acc[4] = {};
            #pragma unroll
            for (int g = 0; g < 4; ++g)
                #pragma unroll
                for (int s = 0; s < 4; ++s)
                    acc[g] = __builtin_amdgcn_mfma_f32_16x16x32_bf16(
                        __builtin_bit_cast(bf16x8, a_[g][s]), b[s], acc[g], 0, 0, 0);
            // epilogue: C layout col = c0t+c, row = wr0+g*16+lb*4+v
            const int mycol = c0t + c;
            if (diagtile) {
                #pragma unroll
                for (int g = 0; g < 4; ++g)
                    #pragma unroll
                    for (int v = 0; v < 4; ++v) {
                        float e = __builtin_amdgcn_exp2f(acc[g][v] * C_LOG2E2);
                        int row = wr0 + g * 16 + lb * 4 + v;
                        sumexp[g][v] += (mycol == row) ? 0.0f : e;   // exclude self
                    }
            } else {
                #pragma unroll
                for (int g = 0; g < 4; ++g)
                    #pragma unroll
                    for (int v = 0; v < 4; ++v)
                        sumexp[g][v] += __builtin_amdgcn_exp2f(acc[g][v] * C_LOG2E2);
            }
        }
    };

    STAGE(0);
    __syncthreads();                                  // fill of tile 0 complete
    for (int t = 0; t < NT; ++t) {
        if (t + 1 < NT) STAGE(t + 1);                 // prefetch, drained at barrier
        COMPUTE(t);
        if (t + 1 < NT) __syncthreads();              // uniform; guards buffer swap
    }

    // reduce across the 16 lanes sharing each row (xor masks 1,2,4,8)
    #pragma unroll
    for (int m = 1; m <= 8; m <<= 1)
        #pragma unroll
        for (int g = 0; g < 4; ++g)
            #pragma unroll
            for (int v = 0; v < 4; ++v)
                sumexp[g][v] += __shfl_xor(sumexp[g][v], m);

    if (l15 == 0) {
        #pragma unroll
        for (int g = 0; g < 4; ++g) {
            int row = wr0 + g * 16 + lb * 4;
            *(f32x4*)&S_part[(size_t)blockIdx.y * N_TOT + row] = sumexp[g];
        }
    }
}

// bf16-pair dot helper (uint = 2 packed bf16)
__device__ inline float bdot(unsigned a, unsigned b) {
    float alo = __uint_as_float(a << 16), ahi = __uint_as_float(a & 0xffff0000u);
    float blo = __uint_as_float(b << 16), bhi = __uint_as_float(b & 0xffff0000u);
    return fmaf(alo, blo, ahi * bhi);
}

// ---------------- kernel 3: per-row loss, block partials ----------------
// lse_r (excl. self) = log(S_r) with S_r = sum_{c != r} exp(2*sim_half);
// contrib = log(S_r) - 2*dot(zn_r, zn_partner).
template <int NSPLIT>
__global__ __launch_bounds__(256) void k_rowsum(const float* __restrict__ S_part,
                                                const __hip_bfloat16* __restrict__ zn_,
                                                float* __restrict__ blk_out) {
    const int r = blockIdx.x * 256 + threadIdx.x;
    float S = 0.0f;
    #pragma unroll
    for (int s = 0; s < NSPLIT; ++s) S += S_part[(size_t)s * N_TOT + r];

    const uint4* pa = (const uint4*)((const __bf16*)zn_ + (size_t)r * DIM);
    const uint4* pb = (const uint4*)((const __bf16*)zn_ + (size_t)(r ^ BATCH) * DIM);
    float dot = 0.0f;
    #pragma unroll
    for (int c = 0; c < DIM / 8; ++c) {
        uint4 ua = pa[c], ub = pb[c];
        dot += bdot(ua.x, ub.x) + bdot(ua.y, ub.y) + bdot(ua.z, ub.z) + bdot(ua.w, ub.w);
    }

    float contrib = __logf(S) - 2.0f * dot;

    #pragma unroll
    for (int m = 1; m < 64; m <<= 1) contrib += __shfl_xor(contrib, m);
    __shared__ float sm[4];
    if ((threadIdx.x & 63) == 0) sm[threadIdx.x >> 6] = contrib;
    __syncthreads();
    if (threadIdx.x == 0) blk_out[blockIdx.x] = sm[0] + sm[1] + sm[2] + sm[3];
}

// ---------------- kernel 4: final scalar ----------------
__global__ void k_final(const float* __restrict__ blk_out, float* __restrict__ out) {
    float v = (threadIdx.x < NROWBLK) ? blk_out[threadIdx.x] : 0.0f;
    #pragma unroll
    for (int m = 1; m < 64; m <<= 1) v += __shfl_xor(v, m);
    if (threadIdx.x == 0) out[0] = v / (float)N_TOT;
}

extern "C" void kernel_launch(void* const* d_in, const int* in_sizes, int n_in,
                              void* d_out, int out_size, void* d_ws, size_t ws_size,
                              hipStream_t stream) {
    const float* zi = (const float*)d_in[0];
    const float* zj = (const float*)d_in[1];
    char* ws = (char*)d_ws;
    __hip_bfloat16* zn = (__hip_bfloat16*)ws;                       // 2 MB
    float* S_part = (float*)(ws + (size_t)2 * 1024 * 1024);
    float* out    = (float*)d_out;

    k_normalize<<<N_TOT / 4, 256, 0, stream>>>(zi, zj, zn);

    const size_t need32 = (size_t)2 * 1024 * 1024 + (size_t)32 * N_TOT * 4 + 256;
    if (ws_size >= need32) {
        constexpr int NS = 32;                        // 1024 blocks = 4/CU
        float* blk = (float*)(ws + (size_t)2 * 1024 * 1024 + (size_t)NS * N_TOT * 4);
        k_main<NS><<<dim3(NROWBLK, NS), 256, 0, stream>>>(zn, S_part);
        k_rowsum<NS><<<NROWBLK, 256, 0, stream>>>(S_part, zn, blk);
        k_final<<<1, 64, 0, stream>>>(blk, out);
    } else {
        constexpr int NS = 16;
        float* blk = (float*)(ws + (size_t)2 * 1024 * 1024 + (size_t)NS * N_TOT * 4);
        k_main<NS><<<dim3(NROWBLK, NS), 256, 0, stream>>>(zn, S_part);
        k_rowsum<NS><<<NROWBLK, 256, 0, stream>>>(S_part, zn, blk);
        k_final<<<1, 64, 0, stream>>>(blk, out);
    }
}

// Round 5
// 36.621 us; speedup vs baseline: 1.7238x; 1.7238x over previous
//
#include <hip/hip_runtime.h>
#include <hip/hip_bf16.h>

// SimCLR loss, MI355X. N=8192 rows, D=128, T=0.5.
// normalize(f32->bf16) -> fused sim-GEMM + sum(exp(2*dot)) (MFMA bf16; fixed-max
// logsumexp since |sim|<=2) -> per-row loss + pos-dot -> scalar reduce.
//
// R5 geometry (attn-ladder shape): 8 waves x 32 rows/wave = 256-row blocks.
// A = 32 VGPR/lane -> allocator keeps it resident (R3 held 84 but remat'd the
// 64-reg A; R4's asm pin made it spill to scratch: VGPR=64, FETCH 54MB).
// B: 64-col tiles staged in LDS via global_load_lds (16B), double-buffered,
// XOR-swizzled (linear LDS dest + inverse-swizzled global src + swizzled read).

#define BATCH 4096
#define N_TOT 8192
#define DIM 128
#define ROWS_PER_WAVE 32
#define WAVES_PER_BLK 8
#define ROWS_PER_BLK 256                 // 8 waves x 32 rows
#define NROWBLK (N_TOT / ROWS_PER_BLK)   // 32
#define TILE_C 64                        // cols per LDS B-tile (16 KB)

// exp(2d) == exp2(d * 2/ln2)
#define C_LOG2E2 2.8853900817779268f

using bf16x8 = __attribute__((ext_vector_type(8))) __bf16;
using f32x4  = __attribute__((ext_vector_type(4))) float;

typedef __attribute__((address_space(1))) const void cg_void;
typedef __attribute__((address_space(3))) void lds_void;
__device__ __forceinline__ void gll16(const void* g, void* l) {
    __builtin_amdgcn_global_load_lds((cg_void*)g, (lds_void*)l, 16, 0, 0);
}

// ---------------- kernel 1: normalize rows, write bf16 ----------------
__global__ __launch_bounds__(256) void k_normalize(const float* __restrict__ zi,
                                                   const float* __restrict__ zj,
                                                   __hip_bfloat16* __restrict__ zn) {
    int row  = blockIdx.x * 4 + (threadIdx.x >> 6);
    int lane = threadIdx.x & 63;
    const float* src = (row < BATCH) ? (zi + (size_t)row * DIM)
                                     : (zj + (size_t)(row - BATCH) * DIM);
    float2 v = ((const float2*)src)[lane];
    float ss = v.x * v.x + v.y * v.y;
    #pragma unroll
    for (int m = 1; m < 64; m <<= 1) ss += __shfl_xor(ss, m);
    float inv = 1.0f / fmaxf(sqrtf(ss), 1e-8f);
    __hip_bfloat162 o;
    o.x = __float2bfloat16(v.x * inv);
    o.y = __float2bfloat16(v.y * inv);
    ((__hip_bfloat162*)(zn + (size_t)row * DIM))[lane] = o;
}

// ---------------- kernel 2: fused sim GEMM + sum of exp(2*dot) ----------------
template <int NCS>
__global__ __launch_bounds__(512, 4) void k_main(const __hip_bfloat16* __restrict__ zn_,
                                                 float* __restrict__ S_part) {
    constexpr int STRIP = N_TOT / NCS;       // cols per block strip (512)
    constexpr int NT    = STRIP / TILE_C;    // B-tiles per block (8)

    __shared__ __align__(16) char Bs[2][TILE_C * 256];

    const int tid  = threadIdx.x;
    const int lane = tid & 63;
    const int wv   = tid >> 6;                        // 0..7
    const int l15  = lane & 15;
    const int lb   = lane >> 4;                       // 0..3
    const int wr0  = blockIdx.x * ROWS_PER_BLK + wv * ROWS_PER_WAVE;
    const int cs0  = blockIdx.y * STRIP;

    const __bf16* zn = (const __bf16*)zn_;

    // A fragments: rows wr0 + g*16 + l15 (g=0,1), k-slice s: k = s*32 + lb*8..+7
    bf16x8 a_[2][4];
    #pragma unroll
    for (int g = 0; g < 2; ++g) {
        const __bf16* p = zn + (size_t)(wr0 + g * 16 + l15) * DIM + lb * 8;
        #pragma unroll
        for (int s = 0; s < 4; ++s)
            a_[g][s] = *(const bf16x8*)(p + s * 32);
    }

    // staging: 1024 granules of 16B per tile; 512 threads -> 2 each.
    // granule m holds global k-chunk j = slot ^ (c&7) of col c  (m = c*16+slot)
    const char* gB = (const char*)(zn + (size_t)cs0 * DIM);
    int srcoff[2];
    #pragma unroll
    for (int i = 0; i < 2; ++i) {
        int m = i * 512 + tid;
        int c = m >> 4, slot = m & 15;
        int j = slot ^ (c & 7);
        srcoff[i] = c * 256 + j * 16;
    }

    auto STAGE = [&](int t) {
        const char* src = gB + (size_t)t * (TILE_C * 256);
        char* dst = Bs[t & 1];
        #pragma unroll
        for (int i = 0; i < 2; ++i)   // LDS dest: wave-uniform base + lane*16
            gll16(src + srcoff[i], dst + i * 8192 + wv * 1024);
    };

    f32x4 sumexp[2] = {};                             // [g] -> 4 rows each

    auto COMPUTE = [&](int t) {
        const char* buf = Bs[t & 1];
        const int c0t = cs0 + t * TILE_C;
        const bool diagtile = ((unsigned)(wr0 - c0t) < (unsigned)TILE_C); // wave-uniform
        #pragma unroll
        for (int cb = 0; cb < 4; ++cb) {
            const int c = cb * 16 + l15;              // local col
            const char* pc = buf + c * 256;
            bf16x8 b[4];
            #pragma unroll
            for (int s = 0; s < 4; ++s)
                b[s] = *(const bf16x8*)(pc + ((lb + s * 4) ^ (c & 7)) * 16);
            f32x4 acc[2] = {};
            #pragma unroll
            for (int g = 0; g < 2; ++g)
                #pragma unroll
                for (int s = 0; s < 4; ++s)
                    acc[g] = __builtin_amdgcn_mfma_f32_16x16x32_bf16(a_[g][s], b[s], acc[g], 0, 0, 0);
            // epilogue: C layout col = c0t+c, row = wr0+g*16+lb*4+v
            const int mycol = c0t + c;
            if (diagtile) {
                #pragma unroll
                for (int g = 0; g < 2; ++g)
                    #pragma unroll
                    for (int v = 0; v < 4; ++v) {
                        float e = __builtin_amdgcn_exp2f(acc[g][v] * C_LOG2E2);
                        int row = wr0 + g * 16 + lb * 4 + v;
                        sumexp[g][v] += (mycol == row) ? 0.0f : e;   // exclude self
                    }
            } else {
                #pragma unroll
                for (int g = 0; g < 2; ++g)
                    #pragma unroll
                    for (int v = 0; v < 4; ++v)
                        sumexp[g][v] += __builtin_amdgcn_exp2f(acc[g][v] * C_LOG2E2);
            }
        }
    };

    STAGE(0);
    __syncthreads();                                  // fill of tile 0 complete
    for (int t = 0; t < NT; ++t) {
        if (t + 1 < NT) STAGE(t + 1);                 // prefetch; drained at barrier
        COMPUTE(t);
        if (t + 1 < NT) __syncthreads();              // guards buffer swap
    }

    // reduce across the 16 lanes sharing each row
    #pragma unroll
    for (int m = 1; m <= 8; m <<= 1)
        #pragma unroll
        for (int g = 0; g < 2; ++g)
            #pragma unroll
            for (int v = 0; v < 4; ++v)
                sumexp[g][v] += __shfl_xor(sumexp[g][v], m);

    if (l15 == 0) {
        #pragma unroll
        for (int g = 0; g < 2; ++g) {
            int row = wr0 + g * 16 + lb * 4;
            *(f32x4*)&S_part[(size_t)blockIdx.y * N_TOT + row] = sumexp[g];
        }
    }
}

// bf16-pair dot helper (uint = 2 packed bf16)
__device__ inline float bdot(unsigned a, unsigned b) {
    float alo = __uint_as_float(a << 16), ahi = __uint_as_float(a & 0xffff0000u);
    float blo = __uint_as_float(b << 16), bhi = __uint_as_float(b & 0xffff0000u);
    return fmaf(alo, blo, ahi * bhi);
}

// ---------------- kernel 3: per-row loss, block partials ----------------
// contrib_r = log(S_r) - 2*dot(zn_r, zn_partner), S_r = sum_{c!=r} exp(2*cos)
template <int NSPLIT>
__global__ __launch_bounds__(256) void k_rowsum(const float* __restrict__ S_part,
                                                const __hip_bfloat16* __restrict__ zn_,
                                                float* __restrict__ blk_out) {
    const int r = blockIdx.x * 256 + threadIdx.x;
    float S = 0.0f;
    #pragma unroll
    for (int s = 0; s < NSPLIT; ++s) S += S_part[(size_t)s * N_TOT + r];

    const uint4* pa = (const uint4*)((const __bf16*)zn_ + (size_t)r * DIM);
    const uint4* pb = (const uint4*)((const __bf16*)zn_ + (size_t)(r ^ BATCH) * DIM);
    float dot = 0.0f;
    #pragma unroll
    for (int c = 0; c < DIM / 8; ++c) {
        uint4 ua = pa[c], ub = pb[c];
        dot += bdot(ua.x, ub.x) + bdot(ua.y, ub.y) + bdot(ua.z, ub.z) + bdot(ua.w, ub.w);
    }

    float contrib = __logf(S) - 2.0f * dot;

    #pragma unroll
    for (int m = 1; m < 64; m <<= 1) contrib += __shfl_xor(contrib, m);
    __shared__ float sm[4];
    if ((threadIdx.x & 63) == 0) sm[threadIdx.x >> 6] = contrib;
    __syncthreads();
    if (threadIdx.x == 0) blk_out[blockIdx.x] = sm[0] + sm[1] + sm[2] + sm[3];
}

// ---------------- kernel 4: final scalar ----------------
__global__ void k_final(const float* __restrict__ blk_out, float* __restrict__ out) {
    float v = (threadIdx.x < NROWBLK) ? blk_out[threadIdx.x] : 0.0f;
    #pragma unroll
    for (int m = 1; m < 64; m <<= 1) v += __shfl_xor(v, m);
    if (threadIdx.x == 0) out[0] = v / (float)N_TOT;
}

extern "C" void kernel_launch(void* const* d_in, const int* in_sizes, int n_in,
                              void* d_out, int out_size, void* d_ws, size_t ws_size,
                              hipStream_t stream) {
    const float* zi = (const float*)d_in[0];
    const float* zj = (const float*)d_in[1];
    char* ws = (char*)d_ws;
    __hip_bfloat16* zn = (__hip_bfloat16*)ws;                       // 2 MB
    float* S_part = (float*)(ws + (size_t)2 * 1024 * 1024);
    float* out    = (float*)d_out;

    constexpr int NS = 16;                            // grid (32,16) = 512 blocks = 2/CU
    float* blk = (float*)(ws + (size_t)2 * 1024 * 1024 + (size_t)NS * N_TOT * 4);

    k_normalize<<<N_TOT / 4, 256, 0, stream>>>(zi, zj, zn);
    k_main<NS><<<dim3(NROWBLK, NS), 512, 0, stream>>>(zn, S_part);
    k_rowsum<NS><<<NROWBLK, 256, 0, stream>>>(S_part, zn, blk);
    k_final<<<1, 64, 0, stream>>>(blk, out);
}